// Round 20
// baseline (57.833 us; speedup 1.0000x reference)
//
#include <hip/hip_runtime.h>

#define T_STEPS 100
#define BATCH 256
#define NIN 784
#define N0 64
#define N1 64
#define N2 10
#define CHUNK (BATCH*N0 + BATCH*N1 + BATCH*N2)   // 35328
#define I0ELEMS (25600*64)

typedef __attribute__((ext_vector_type(8))) short short8;
typedef __attribute__((ext_vector_type(4))) float f32x4;

__device__ inline short bf16_rne(float x) {
  unsigned u = __float_as_uint(x);
  unsigned h = (u + 0x7FFFu + ((u >> 16) & 1u)) >> 16;
  return (short)h;
}
__device__ inline float bf16_val(short h) {
  return __uint_as_float(((unsigned)(unsigned short)h) << 16);
}

// ---------------------------------------------------------------------------
// Kernel 0: pack W0 (f32 [64][784]) into bf16x3 fragment-coalesced layout
// W0p[c][p][ct][lane][e]: c = 32-k chunk (25, zero-pad k>=784), lane = MFMA
// B-frag lane (col = ct*16 + (l&15), k = c*32 + (l>>4)*8 + e). (R12, passed.)
// ---------------------------------------------------------------------------
__global__ __launch_bounds__(256) void prep_w0_pack(
    const float* __restrict__ W0, short* __restrict__ W0p) {
  int idx = blockIdx.x * 256 + threadIdx.x;      // 0..153599
  int e  = idx & 7;
  int r1 = idx >> 3;
  int l  = r1 & 63;
  int r2 = r1 >> 6;
  int ct = r2 & 3;
  int r3 = r2 >> 2;
  int p  = r3 % 3;
  int c  = r3 / 3;                               // 0..24
  int k   = c * 32 + (l >> 4) * 8 + e;
  int col = ct * 16 + (l & 15);
  float w = (k < NIN) ? W0[col * NIN + k] : 0.0f;
  short h0 = bf16_rne(w);
  float rr1 = w - bf16_val(h0);
  short h1 = bf16_rne(rr1);
  float rr2 = rr1 - bf16_val(h1);
  short h2 = bf16_rne(rr2);
  W0p[idx] = (p == 0) ? h0 : (p == 1) ? h1 : h2;
}

// ---------------------------------------------------------------------------
// Kernel 1: I0T = X @ W0^T + b0 via bf16x3 MFMA — R19's pipeline with BM=16:
// block = 16 rows x 64 cols, 4 waves = k-splits {192,192,192,224-pad};
// grid 1600 -> 6400 waves (~55-65% occupancy, 3x R19's TLP). B from packed
// fragment-coalesced W0p (12 x 1KB loads/chunk); A direct-global + rotation
// prefetch; 6-product order; epilogue LDS reduce (+bias) -> b-major I0T.
// Per-element FP chains bit-identical to R19/R10 (passed absmax 0).
// ---------------------------------------------------------------------------
__global__ __launch_bounds__(256, 2) void gemm0_kernel(
    const float* __restrict__ X, const short* __restrict__ W0p,
    const float* __restrict__ b0, float* __restrict__ I0T) {
  __shared__ float red[4][16][68];               // 17.4 KB wave-partials

  const int tid = threadIdx.x;
  const int r0  = blockIdx.x * 16;
  const int wid = tid >> 6;                      // wave 0..3 = k-split
  const int l   = tid & 63;
  const int lr  = l & 15;                        // frag row/col lane
  const int lk  = l >> 4;                        // frag k-octet lane

  const int kbeg = wid * 192;
  const int ccnt = (wid < 3) ? 6 : 7;            // last: 208 real k + 16 pad

  f32x4 acc[4];                                  // [col-tile]
#pragma unroll
  for (int ct = 0; ct < 4; ++ct) acc[ct] = f32x4{0.f, 0.f, 0.f, 0.f};

  const float*  xr0 = X + (size_t)(r0 + lr) * NIN;
  const short8* wp8 = (const short8*)W0p;        // packed layout

  // ---- prologue: A-load chunk 0
  float4 cxa, cxb;
  {
    const int k0 = kbeg + lk * 8;
    if (k0 < NIN) {
      cxa = *(const float4*)(xr0 + k0);
      cxb = *(const float4*)(xr0 + k0 + 4);
    } else {
      cxa = cxb = float4{0.f, 0.f, 0.f, 0.f};
    }
  }

  for (int c = 0; c < ccnt; ++c) {
    const int kb = kbeg + c * 32;
    const int g  = (kbeg >> 5) + c;              // global 32-k chunk 0..24
    const bool more = (c + 1 < ccnt);

    // ---- issue next chunk's A-loads (latency hides under this chunk)
    float4 nxa, nxb;
    if (more) {
      const int k0n = kb + 32 + lk * 8;
      if (k0n < NIN) {
        nxa = *(const float4*)(xr0 + k0n);
        nxb = *(const float4*)(xr0 + k0n + 4);
      } else {
        nxa = nxb = float4{0.f, 0.f, 0.f, 0.f};
      }
    }

    // ---- batch-issue this chunk's 12 B-loads (packed, fully coalesced)
    short8 cb[4][3];
#pragma unroll
    for (int ct = 0; ct < 4; ++ct) {
#pragma unroll
      for (int p = 0; p < 3; ++p)
        cb[ct][p] = wp8[(size_t)((g * 3 + p) * 4 + ct) * 64 + l];
    }

    // ---- convert this chunk's A to bf16x3 fragments (overlaps B latency)
    short8 a0[3];
    {
      float xs[8] = {cxa.x, cxa.y, cxa.z, cxa.w, cxb.x, cxb.y, cxb.z, cxb.w};
#pragma unroll
      for (int e = 0; e < 8; ++e) {
        float x  = xs[e];
        short h0 = bf16_rne(x);   float rr1 = x - bf16_val(h0);
        short h1 = bf16_rne(rr1); float rr2 = rr1 - bf16_val(h1);
        a0[0][e] = h0; a0[1][e] = h1; a0[2][e] = bf16_rne(rr2);
      }
    }

    // ---- MFMA: 4 col-tiles x 6 products (R19 order)
#pragma unroll
    for (int ct = 0; ct < 4; ++ct) {
      f32x4 a = acc[ct];
      a = __builtin_amdgcn_mfma_f32_16x16x32_bf16(a0[2], cb[ct][0], a, 0, 0, 0);
      a = __builtin_amdgcn_mfma_f32_16x16x32_bf16(a0[0], cb[ct][2], a, 0, 0, 0);
      a = __builtin_amdgcn_mfma_f32_16x16x32_bf16(a0[1], cb[ct][1], a, 0, 0, 0);
      a = __builtin_amdgcn_mfma_f32_16x16x32_bf16(a0[1], cb[ct][0], a, 0, 0, 0);
      a = __builtin_amdgcn_mfma_f32_16x16x32_bf16(a0[0], cb[ct][1], a, 0, 0, 0);
      a = __builtin_amdgcn_mfma_f32_16x16x32_bf16(a0[0], cb[ct][0], a, 0, 0, 0);
      acc[ct] = a;
    }

    // ---- rotate prefetched A into current
    if (more) { cxa = nxa; cxb = nxb; }
  }

  // ---- epilogue: wave-partials -> LDS  (C/D: col=l&15, row=(l>>4)*4+r)
#pragma unroll
  for (int ct = 0; ct < 4; ++ct)
#pragma unroll
    for (int r = 0; r < 4; ++r)
      red[wid][lk * 4 + r][ct * 16 + lr] = acc[ct][r];
  __syncthreads();

  // ---- reduce 4 partials + bias (R19 order), write b-major I0T
  {
    const int t0  = r0 >> 8;
    const int bb0 = r0 & 255;
    int row = tid >> 4, q = tid & 15;            // 256 threads = 16 rows x 16 q
    float4 v  = *(const float4*)&red[0][row][q * 4];
    float4 u1 = *(const float4*)&red[1][row][q * 4];
    float4 u2 = *(const float4*)&red[2][row][q * 4];
    float4 u3 = *(const float4*)&red[3][row][q * 4];
    v.x += u1.x; v.y += u1.y; v.z += u1.z; v.w += u1.w;
    v.x += u2.x; v.y += u2.y; v.z += u2.z; v.w += u2.w;
    v.x += u3.x; v.y += u3.y; v.z += u3.z; v.w += u3.w;
    float4 bv = ((const float4*)b0)[q];
    v.x += bv.x; v.y += bv.y; v.z += bv.z; v.w += bv.w;
    ((float4*)I0T)[((size_t)(bb0 + row) * T_STEPS + t0) * 16 + q] = v;
  }
}

// ---------------------------------------------------------------------------
// Kernel 2: one block per batch element (R9's lean fused body, measured).
// ---------------------------------------------------------------------------
__global__ __launch_bounds__(256) void fused_kernel(
    const float* __restrict__ I0T,
    const float* __restrict__ W1, const float* __restrict__ b1,
    const float* __restrict__ W2, const float* __restrict__ b2,
    float* __restrict__ out) {
  __shared__ float bufA[112][68];
  __shared__ float sW1t[64][68];
  __shared__ float sW2[N2][68];
  __shared__ float sI2[T_STEPS][N2];

  const int b   = blockIdx.x;
  const int tid = threadIdx.x;
  const int j   = tid & 63;
  const int tq  = tid >> 6;
  float* outSpk = out;
  float* laySpk = out + T_STEPS * BATCH * N2;

  {
    const float4* src = (const float4*)I0T + (size_t)b * (T_STEPS * 16);
    for (int idx = tid; idx < T_STEPS * 16; idx += 256) {
      float4 v = src[idx];
      int t = idx >> 4, j4 = idx & 15;
      *(float4*)&bufA[t][j4 * 4] = v;
    }
  }
  __syncthreads();

  if (tq == 0) {
    float v = 0.0f;
#pragma unroll
    for (int g = 0; g < 4; ++g) {
      float ic[25];
#pragma unroll
      for (int i = 0; i < 25; ++i) ic[i] = bufA[g * 25 + i][j];
#pragma unroll
      for (int i = 0; i < 25; ++i) {
        v = v + 0.05f * ((0.0f - v) + ic[i]);
        float z = (v > 1.0f) ? 1.0f : 0.0f;
        v -= z;
        ic[i] = z;
      }
#pragma unroll
      for (int i = 0; i < 25; ++i) bufA[g * 25 + i][j] = ic[i];
    }
  } else {
    for (int idx = tid - 64; idx < 64 * 16; idx += 192) {
      int i = idx >> 4, jv = idx & 15;
      float4 wv = *(const float4*)(W1 + (size_t)i * 64 + jv * 4);
      sW1t[jv * 4 + 0][i] = wv.x;
      sW1t[jv * 4 + 1][i] = wv.y;
      sW1t[jv * 4 + 2][i] = wv.z;
      sW1t[jv * 4 + 3][i] = wv.w;
    }
    for (int idx = tid - 64; idx < N2 * 16; idx += 192) {
      int o = idx >> 4, jv = idx & 15;
      *(float4*)&sW2[o][jv * 4] = *(const float4*)(W2 + (size_t)o * 64 + jv * 4);
    }
  }
  __syncthreads();

  for (int idx = tid; idx < T_STEPS * 16; idx += 256) {
    int t = idx >> 4, jv = idx & 15;
    *(float4*)(laySpk + (size_t)t * CHUNK + b * 64 + jv * 4) =
        *(const float4*)&bufA[t][jv * 4];
  }

  const int iq = tid & 15;
  const int ts = tid >> 4;
  float g1[4][7];
  {
    float4 bias = *(const float4*)(b1 + iq * 4);
#pragma unroll
    for (int tt = 0; tt < 7; ++tt) {
      g1[0][tt] = bias.x; g1[1][tt] = bias.y; g1[2][tt] = bias.z; g1[3][tt] = bias.w;
    }
#pragma unroll
    for (int jq = 0; jq < 16; ++jq) {
      float4 zv4[7];
#pragma unroll
      for (int tt = 0; tt < 7; ++tt)
        zv4[tt] = *(const float4*)&bufA[ts * 7 + tt][jq * 4];
      float4 w4[4];
#pragma unroll
      for (int e = 0; e < 4; ++e)
        w4[e] = *(const float4*)&sW1t[jq * 4 + e][iq * 4];
#pragma unroll
      for (int e = 0; e < 4; ++e) {
#pragma unroll
        for (int tt = 0; tt < 7; ++tt) {
          float zv = ((const float*)&zv4[tt])[e];
          g1[0][tt] = fmaf(zv, w4[e].x, g1[0][tt]);
          g1[1][tt] = fmaf(zv, w4[e].y, g1[1][tt]);
          g1[2][tt] = fmaf(zv, w4[e].z, g1[2][tt]);
          g1[3][tt] = fmaf(zv, w4[e].w, g1[3][tt]);
        }
      }
    }
  }
  __syncthreads();
#pragma unroll
  for (int tt = 0; tt < 7; ++tt) {
    float4 o = {g1[0][tt], g1[1][tt], g1[2][tt], g1[3][tt]};
    *(float4*)&bufA[ts * 7 + tt][iq * 4] = o;
  }
  __syncthreads();

  if (tq == 0) {
    float v = 0.0f;
#pragma unroll
    for (int g = 0; g < 4; ++g) {
      float ic[25];
#pragma unroll
      for (int i = 0; i < 25; ++i) ic[i] = bufA[g * 25 + i][j];
#pragma unroll
      for (int i = 0; i < 25; ++i) {
        v = v + 0.05f * ((0.0f - v) + ic[i]);
        float z = (v > 1.0f) ? 1.0f : 0.0f;
        v -= z;
        ic[i] = z;
      }
#pragma unroll
      for (int i = 0; i < 25; ++i) bufA[g * 25 + i][j] = ic[i];
    }
  }
  __syncthreads();

  for (int idx = tid; idx < T_STEPS * 16; idx += 256) {
    int t = idx >> 4, jv = idx & 15;
    *(float4*)(laySpk + (size_t)t * CHUNK + BATCH * N0 + b * 64 + jv * 4) =
        *(const float4*)&bufA[t][jv * 4];
  }

  for (int idx = tid; idx < T_STEPS * N2; idx += 256) {
    int t = idx / N2, o = idx % N2;
    float a = b2[o];
#pragma unroll
    for (int jq = 0; jq < 16; ++jq) {
      float4 z = *(const float4*)&bufA[t][jq * 4];
      float4 wv = *(const float4*)&sW2[o][jq * 4];
      a += z.x * wv.x;
      a += z.y * wv.y;
      a += z.z * wv.z;
      a += z.w * wv.w;
    }
    sI2[t][o] = a;
  }
  __syncthreads();

  if (tid < N2) {
    float v = 0.0f;
#pragma unroll
    for (int g = 0; g < 4; ++g) {
      float ic[25];
#pragma unroll
      for (int i = 0; i < 25; ++i) ic[i] = sI2[g * 25 + i][tid];
#pragma unroll
      for (int i = 0; i < 25; ++i) {
        v = v + 0.05f * ((0.0f - v) + ic[i]);
        float z = (v > 1.0f) ? 1.0f : 0.0f;
        v -= z;
        ic[i] = z;
      }
#pragma unroll
      for (int i = 0; i < 25; ++i) sI2[g * 25 + i][tid] = ic[i];
    }
  }
  __syncthreads();

  for (int idx = tid; idx < T_STEPS * N2; idx += 256) {
    int t = idx / N2, o = idx % N2;
    float z = sI2[t][o];
    outSpk[(size_t)t * (BATCH * N2) + b * N2 + o] = z;
    laySpk[(size_t)t * CHUNK + BATCH * (N0 + N1) + b * N2 + o] = z;
  }
}

extern "C" void kernel_launch(void* const* d_in, const int* in_sizes, int n_in,
                              void* d_out, int out_size, void* d_ws, size_t ws_size,
                              hipStream_t stream) {
  const float* inp = (const float*)d_in[0];
  const float* W0  = (const float*)d_in[1];
  const float* b0  = (const float*)d_in[2];
  const float* W1  = (const float*)d_in[3];
  const float* b1  = (const float*)d_in[4];
  const float* W2  = (const float*)d_in[5];
  const float* b2  = (const float*)d_in[6];

  float* I0T = (float*)d_ws;                 // 6.55 MB, b-major [b][t][j]
  short* W0p = (short*)(I0T + I0ELEMS);      // 300 KB packed bf16x3 fragments

  prep_w0_pack<<<dim3(600), dim3(256), 0, stream>>>(W0, W0p);
  gemm0_kernel<<<dim3(1600), dim3(256), 0, stream>>>(inp, W0p, b0, I0T);
  fused_kernel<<<dim3(BATCH), dim3(256), 0, stream>>>(I0T, W1, b1, W2, b2,
                                                      (float*)d_out);
}

// Round 21
// 53.645 us; speedup vs baseline: 1.0781x; 1.0781x over previous
//
#include <hip/hip_runtime.h>

#define T_STEPS 100
#define BATCH 256
#define NIN 784
#define N0 64
#define N1 64
#define N2 10
#define CHUNK (BATCH*N0 + BATCH*N1 + BATCH*N2)   // 35328
#define I0ELEMS (25600*64)
#define NCHP 28                                  // packed 32-k chunks (896/32)

typedef __attribute__((ext_vector_type(8))) short short8;
typedef __attribute__((ext_vector_type(4))) float f32x4;

__device__ inline short bf16_rne(float x) {
  unsigned u = __float_as_uint(x);
  unsigned h = (u + 0x7FFFu + ((u >> 16) & 1u)) >> 16;
  return (short)h;
}
__device__ inline float bf16_val(short h) {
  return __uint_as_float(((unsigned)(unsigned short)h) << 16);
}

// ---------------------------------------------------------------------------
// Kernel 0: pack W0 (f32 [64][784]) into bf16x3 fragment-coalesced layout,
// 28 chunks of 32 k (zero-pad k>=784). W0p[c][p][ct][lane][e]; lane = MFMA
// B-frag lane (col = ct*16 + (l&15), k = c*32 + (l>>4)*8 + e).
// ---------------------------------------------------------------------------
__global__ __launch_bounds__(256) void prep_w0_pack(
    const float* __restrict__ W0, short* __restrict__ W0p) {
  int idx = blockIdx.x * 256 + threadIdx.x;      // 0..172031
  if (idx >= NCHP * 3 * 4 * 64 * 8) return;
  int e  = idx & 7;
  int r1 = idx >> 3;
  int l  = r1 & 63;
  int r2 = r1 >> 6;
  int ct = r2 & 3;
  int r3 = r2 >> 2;
  int p  = r3 % 3;
  int c  = r3 / 3;                               // 0..27
  int k   = c * 32 + (l >> 4) * 8 + e;
  int col = ct * 16 + (l & 15);
  float w = (k < NIN) ? W0[col * NIN + k] : 0.0f;
  short h0 = bf16_rne(w);
  float rr1 = w - bf16_val(h0);
  short h1 = bf16_rne(rr1);
  float rr2 = rr1 - bf16_val(h1);
  short h2 = bf16_rne(rr2);
  W0p[idx] = (p == 0) ? h0 : (p == 1) ? h1 : h2;
}

// ---------------------------------------------------------------------------
// Kernel 1: I0T = X @ W0^T + b0 via bf16x3 MFMA. R19 geometry (BM=32, 4 waves,
// packed-coalesced B, grid 800) with UNIFORM 7-chunk k-splits (4 x 224, K
// padded to 896) -> compile-time trip count -> #pragma unroll lets the
// scheduler hoist A/B loads 2-3 chunks deep (the concurrency R19 lacked).
// 6-product order unchanged; epilogue LDS reduce (s ascending + bias last).
// ---------------------------------------------------------------------------
__global__ __launch_bounds__(256, 2) void gemm0_kernel(
    const float* __restrict__ X, const short* __restrict__ W0p,
    const float* __restrict__ b0, float* __restrict__ I0T) {
  __shared__ float red[4][32][68];               // 34.8 KB wave-partials

  const int tid = threadIdx.x;
  const int r0  = blockIdx.x * 32;
  const int wid = tid >> 6;                      // wave 0..3 = k-split
  const int l   = tid & 63;
  const int lr  = l & 15;                        // frag row/col lane
  const int lk  = l >> 4;                        // frag k-octet lane

  const int kbeg = wid * 224;                    // uniform splits: 4 x 224

  f32x4 acc[2][4];
#pragma unroll
  for (int rt = 0; rt < 2; ++rt)
#pragma unroll
    for (int ct = 0; ct < 4; ++ct) acc[rt][ct] = f32x4{0.f, 0.f, 0.f, 0.f};

  const float*  xr0 = X + (size_t)(r0 + lr) * NIN;
  const float*  xr1 = xr0 + 16 * NIN;
  const short8* wp8 = (const short8*)W0p;        // packed layout

#pragma unroll
  for (int c = 0; c < 7; ++c) {                  // compile-time trip count
    const int k0 = kbeg + c * 32 + lk * 8;
    const int g  = wid * 7 + c;                  // packed chunk 0..27

    // ---- A: 8 f32 per row-tile (guarded pad tail)
    float4 xa0, xb0, xa1, xb1;
    if (k0 < NIN) {
      xa0 = *(const float4*)(xr0 + k0);
      xb0 = *(const float4*)(xr0 + k0 + 4);
      xa1 = *(const float4*)(xr1 + k0);
      xb1 = *(const float4*)(xr1 + k0 + 4);
    } else {
      xa0 = xb0 = xa1 = xb1 = float4{0.f, 0.f, 0.f, 0.f};
    }

    // ---- B: 12 fully-coalesced 1KB loads from packed W0p
    short8 cb[4][3];
#pragma unroll
    for (int ct = 0; ct < 4; ++ct) {
#pragma unroll
      for (int p = 0; p < 3; ++p)
        cb[ct][p] = wp8[(size_t)((g * 3 + p) * 4 + ct) * 64 + l];
    }

    // ---- convert A to bf16x3 fragments (overlaps load latency)
    short8 a0[3], a1[3];
    {
      float xs0[8] = {xa0.x, xa0.y, xa0.z, xa0.w, xb0.x, xb0.y, xb0.z, xb0.w};
      float xs1[8] = {xa1.x, xa1.y, xa1.z, xa1.w, xb1.x, xb1.y, xb1.z, xb1.w};
#pragma unroll
      for (int e = 0; e < 8; ++e) {
        float x  = xs0[e];
        short h0 = bf16_rne(x);   float rr1 = x - bf16_val(h0);
        short h1 = bf16_rne(rr1); float rr2 = rr1 - bf16_val(h1);
        a0[0][e] = h0; a0[1][e] = h1; a0[2][e] = bf16_rne(rr2);
        x  = xs1[e];
        h0 = bf16_rne(x);   rr1 = x - bf16_val(h0);
        h1 = bf16_rne(rr1); rr2 = rr1 - bf16_val(h1);
        a1[0][e] = h0; a1[1][e] = h1; a1[2][e] = bf16_rne(rr2);
      }
    }

    // ---- MFMA: 2 row-tiles x 4 col-tiles x 6 products (fixed order)
#pragma unroll
    for (int ct = 0; ct < 4; ++ct) {
      {
        f32x4 a = acc[0][ct];
        a = __builtin_amdgcn_mfma_f32_16x16x32_bf16(a0[2], cb[ct][0], a, 0, 0, 0);
        a = __builtin_amdgcn_mfma_f32_16x16x32_bf16(a0[0], cb[ct][2], a, 0, 0, 0);
        a = __builtin_amdgcn_mfma_f32_16x16x32_bf16(a0[1], cb[ct][1], a, 0, 0, 0);
        a = __builtin_amdgcn_mfma_f32_16x16x32_bf16(a0[1], cb[ct][0], a, 0, 0, 0);
        a = __builtin_amdgcn_mfma_f32_16x16x32_bf16(a0[0], cb[ct][1], a, 0, 0, 0);
        a = __builtin_amdgcn_mfma_f32_16x16x32_bf16(a0[0], cb[ct][0], a, 0, 0, 0);
        acc[0][ct] = a;
      }
      {
        f32x4 a = acc[1][ct];
        a = __builtin_amdgcn_mfma_f32_16x16x32_bf16(a1[2], cb[ct][0], a, 0, 0, 0);
        a = __builtin_amdgcn_mfma_f32_16x16x32_bf16(a1[0], cb[ct][2], a, 0, 0, 0);
        a = __builtin_amdgcn_mfma_f32_16x16x32_bf16(a1[1], cb[ct][1], a, 0, 0, 0);
        a = __builtin_amdgcn_mfma_f32_16x16x32_bf16(a1[1], cb[ct][0], a, 0, 0, 0);
        a = __builtin_amdgcn_mfma_f32_16x16x32_bf16(a1[0], cb[ct][1], a, 0, 0, 0);
        a = __builtin_amdgcn_mfma_f32_16x16x32_bf16(a1[0], cb[ct][0], a, 0, 0, 0);
        acc[1][ct] = a;
      }
    }
  }

  // ---- epilogue: wave-partials -> LDS  (C/D: col=l&15, row=(l>>4)*4+r)
#pragma unroll
  for (int rt = 0; rt < 2; ++rt)
#pragma unroll
    for (int ct = 0; ct < 4; ++ct)
#pragma unroll
      for (int r = 0; r < 4; ++r)
        red[wid][rt * 16 + lk * 4 + r][ct * 16 + lr] = acc[rt][ct][r];
  __syncthreads();

  // ---- reduce 4 partials (s ascending) + bias, write b-major I0T
  const int t0  = r0 >> 8;
  const int bb0 = r0 & 255;
  for (int idx = tid; idx < 32 * 16; idx += 256) {
    int row = idx >> 4, q = idx & 15;
    float4 v  = *(const float4*)&red[0][row][q * 4];
    float4 u1 = *(const float4*)&red[1][row][q * 4];
    float4 u2 = *(const float4*)&red[2][row][q * 4];
    float4 u3 = *(const float4*)&red[3][row][q * 4];
    v.x += u1.x; v.y += u1.y; v.z += u1.z; v.w += u1.w;
    v.x += u2.x; v.y += u2.y; v.z += u2.z; v.w += u2.w;
    v.x += u3.x; v.y += u3.y; v.z += u3.z; v.w += u3.w;
    float4 bv = ((const float4*)b0)[q];
    v.x += bv.x; v.y += bv.y; v.z += bv.z; v.w += bv.w;
    ((float4*)I0T)[((size_t)(bb0 + row) * T_STEPS + t0) * 16 + q] = v;
  }
}

// ---------------------------------------------------------------------------
// Kernel 2: one block per batch element (R9's lean fused body, measured).
// ---------------------------------------------------------------------------
__global__ __launch_bounds__(256) void fused_kernel(
    const float* __restrict__ I0T,
    const float* __restrict__ W1, const float* __restrict__ b1,
    const float* __restrict__ W2, const float* __restrict__ b2,
    float* __restrict__ out) {
  __shared__ float bufA[112][68];
  __shared__ float sW1t[64][68];
  __shared__ float sW2[N2][68];
  __shared__ float sI2[T_STEPS][N2];

  const int b   = blockIdx.x;
  const int tid = threadIdx.x;
  const int j   = tid & 63;
  const int tq  = tid >> 6;
  float* outSpk = out;
  float* laySpk = out + T_STEPS * BATCH * N2;

  {
    const float4* src = (const float4*)I0T + (size_t)b * (T_STEPS * 16);
    for (int idx = tid; idx < T_STEPS * 16; idx += 256) {
      float4 v = src[idx];
      int t = idx >> 4, j4 = idx & 15;
      *(float4*)&bufA[t][j4 * 4] = v;
    }
  }
  __syncthreads();

  if (tq == 0) {
    float v = 0.0f;
#pragma unroll
    for (int g = 0; g < 4; ++g) {
      float ic[25];
#pragma unroll
      for (int i = 0; i < 25; ++i) ic[i] = bufA[g * 25 + i][j];
#pragma unroll
      for (int i = 0; i < 25; ++i) {
        v = v + 0.05f * ((0.0f - v) + ic[i]);
        float z = (v > 1.0f) ? 1.0f : 0.0f;
        v -= z;
        ic[i] = z;
      }
#pragma unroll
      for (int i = 0; i < 25; ++i) bufA[g * 25 + i][j] = ic[i];
    }
  } else {
    for (int idx = tid - 64; idx < 64 * 16; idx += 192) {
      int i = idx >> 4, jv = idx & 15;
      float4 wv = *(const float4*)(W1 + (size_t)i * 64 + jv * 4);
      sW1t[jv * 4 + 0][i] = wv.x;
      sW1t[jv * 4 + 1][i] = wv.y;
      sW1t[jv * 4 + 2][i] = wv.z;
      sW1t[jv * 4 + 3][i] = wv.w;
    }
    for (int idx = tid - 64; idx < N2 * 16; idx += 192) {
      int o = idx >> 4, jv = idx & 15;
      *(float4*)&sW2[o][jv * 4] = *(const float4*)(W2 + (size_t)o * 64 + jv * 4);
    }
  }
  __syncthreads();

  for (int idx = tid; idx < T_STEPS * 16; idx += 256) {
    int t = idx >> 4, jv = idx & 15;
    *(float4*)(laySpk + (size_t)t * CHUNK + b * 64 + jv * 4) =
        *(const float4*)&bufA[t][jv * 4];
  }

  const int iq = tid & 15;
  const int ts = tid >> 4;
  float g1[4][7];
  {
    float4 bias = *(const float4*)(b1 + iq * 4);
#pragma unroll
    for (int tt = 0; tt < 7; ++tt) {
      g1[0][tt] = bias.x; g1[1][tt] = bias.y; g1[2][tt] = bias.z; g1[3][tt] = bias.w;
    }
#pragma unroll
    for (int jq = 0; jq < 16; ++jq) {
      float4 zv4[7];
#pragma unroll
      for (int tt = 0; tt < 7; ++tt)
        zv4[tt] = *(const float4*)&bufA[ts * 7 + tt][jq * 4];
      float4 w4[4];
#pragma unroll
      for (int e = 0; e < 4; ++e)
        w4[e] = *(const float4*)&sW1t[jq * 4 + e][iq * 4];
#pragma unroll
      for (int e = 0; e < 4; ++e) {
#pragma unroll
        for (int tt = 0; tt < 7; ++tt) {
          float zv = ((const float*)&zv4[tt])[e];
          g1[0][tt] = fmaf(zv, w4[e].x, g1[0][tt]);
          g1[1][tt] = fmaf(zv, w4[e].y, g1[1][tt]);
          g1[2][tt] = fmaf(zv, w4[e].z, g1[2][tt]);
          g1[3][tt] = fmaf(zv, w4[e].w, g1[3][tt]);
        }
      }
    }
  }
  __syncthreads();
#pragma unroll
  for (int tt = 0; tt < 7; ++tt) {
    float4 o = {g1[0][tt], g1[1][tt], g1[2][tt], g1[3][tt]};
    *(float4*)&bufA[ts * 7 + tt][iq * 4] = o;
  }
  __syncthreads();

  if (tq == 0) {
    float v = 0.0f;
#pragma unroll
    for (int g = 0; g < 4; ++g) {
      float ic[25];
#pragma unroll
      for (int i = 0; i < 25; ++i) ic[i] = bufA[g * 25 + i][j];
#pragma unroll
      for (int i = 0; i < 25; ++i) {
        v = v + 0.05f * ((0.0f - v) + ic[i]);
        float z = (v > 1.0f) ? 1.0f : 0.0f;
        v -= z;
        ic[i] = z;
      }
#pragma unroll
      for (int i = 0; i < 25; ++i) bufA[g * 25 + i][j] = ic[i];
    }
  }
  __syncthreads();

  for (int idx = tid; idx < T_STEPS * 16; idx += 256) {
    int t = idx >> 4, jv = idx & 15;
    *(float4*)(laySpk + (size_t)t * CHUNK + BATCH * N0 + b * 64 + jv * 4) =
        *(const float4*)&bufA[t][jv * 4];
  }

  for (int idx = tid; idx < T_STEPS * N2; idx += 256) {
    int t = idx / N2, o = idx % N2;
    float a = b2[o];
#pragma unroll
    for (int jq = 0; jq < 16; ++jq) {
      float4 z = *(const float4*)&bufA[t][jq * 4];
      float4 wv = *(const float4*)&sW2[o][jq * 4];
      a += z.x * wv.x;
      a += z.y * wv.y;
      a += z.z * wv.z;
      a += z.w * wv.w;
    }
    sI2[t][o] = a;
  }
  __syncthreads();

  if (tid < N2) {
    float v = 0.0f;
#pragma unroll
    for (int g = 0; g < 4; ++g) {
      float ic[25];
#pragma unroll
      for (int i = 0; i < 25; ++i) ic[i] = sI2[g * 25 + i][tid];
#pragma unroll
      for (int i = 0; i < 25; ++i) {
        v = v + 0.05f * ((0.0f - v) + ic[i]);
        float z = (v > 1.0f) ? 1.0f : 0.0f;
        v -= z;
        ic[i] = z;
      }
#pragma unroll
      for (int i = 0; i < 25; ++i) sI2[g * 25 + i][tid] = ic[i];
    }
  }
  __syncthreads();

  for (int idx = tid; idx < T_STEPS * N2; idx += 256) {
    int t = idx / N2, o = idx % N2;
    float z = sI2[t][o];
    outSpk[(size_t)t * (BATCH * N2) + b * N2 + o] = z;
    laySpk[(size_t)t * CHUNK + BATCH * (N0 + N1) + b * N2 + o] = z;
  }
}

extern "C" void kernel_launch(void* const* d_in, const int* in_sizes, int n_in,
                              void* d_out, int out_size, void* d_ws, size_t ws_size,
                              hipStream_t stream) {
  const float* inp = (const float*)d_in[0];
  const float* W0  = (const float*)d_in[1];
  const float* b0  = (const float*)d_in[2];
  const float* W1  = (const float*)d_in[3];
  const float* b1  = (const float*)d_in[4];
  const float* W2  = (const float*)d_in[5];
  const float* b2  = (const float*)d_in[6];

  float* I0T = (float*)d_ws;                 // 6.55 MB, b-major [b][t][j]
  short* W0p = (short*)(I0T + I0ELEMS);      // 344 KB packed bf16x3 fragments

  prep_w0_pack<<<dim3(672), dim3(256), 0, stream>>>(W0, W0p);
  gemm0_kernel<<<dim3(800), dim3(256), 0, stream>>>(inp, W0p, b0, I0T);
  fused_kernel<<<dim3(BATCH), dim3(256), 0, stream>>>(I0T, W1, b1, W2, b2,
                                                      (float*)d_out);
}